// Round 1
// baseline (1176.623 us; speedup 1.0000x reference)
//
#include <hip/hip_runtime.h>
#include <math.h>

// Problem: out[b,m,v,t,s] = softmax_s( sum_o (W1·X)[o,t] * (W2·X)[o,s] )
// per (b,v,m) slice X[c,t] = x[b,c,t,v,m].
// B=16, C=256, T=256, V=25, M=2, O=128.
//
// Stage 1: s12 = [W1;W2] (256x256) · X_b (256x12800) per b, written to ws in
//          permuted layout ws[b_local][vm][o2][t] (scattered stores, L2 merges).
// Stage 2: per (b,vm): scores = s1^T s2 (256x256, K=128) + fused row softmax,
//          coalesced reads from ws, coalesced float4 writes to out.
// Multi-pass over b sized by ws_size (13.1 MB per b needed).

#define C_DIM 256
#define T_DIM 256
#define V_DIM 25
#define M_DIM 2
#define O_DIM 128
#define N_DIM (T_DIM * V_DIM * M_DIM) /* 12800 */
#define VM    (V_DIM * M_DIM)         /* 50 */

// ---------------- Stage 1: 128x128-tile fp32 GEMM, permuted store ------------
__global__ __launch_bounds__(256)
void stage1_gemm(const float* __restrict__ x, const float* __restrict__ W1,
                 const float* __restrict__ W2, float* __restrict__ ws, int b0) {
    const int b = b0 + blockIdx.z;
    const float* xb = x + (size_t)b * C_DIM * N_DIM;
    float* outb = ws + (size_t)blockIdx.z * VM * (O_DIM * 2 * T_DIM);
    const int o0 = blockIdx.y * 128;           // 0 or 128 (W1 vs W2 half)
    const int n0 = blockIdx.x * 128;
    const float* Wsrc = (o0 == 0) ? W1 : W2;

    __shared__ float Wt[16][132];   // [k][o2]  (+4 pad: float4-aligned rows)
    __shared__ float Xt[16][132];   // [k][n]

    const int tid = threadIdx.x;
    const int ty = tid >> 4;        // 0..15 -> o2 micro-row block
    const int tx = tid & 15;        // 0..15 -> n  micro-col block

    // load mappings
    const int wo = tid >> 1;            // 0..127  (o row within tile)
    const int wk = (tid & 1) * 8;       // 0 or 8  (k sub-block)
    const int xk = tid >> 4;            // 0..15   (k row)
    const int xn = (tid & 15) * 8;      // 0..120  (n col)

    float acc[8][8] = {};

    for (int kc = 0; kc < C_DIM; kc += 16) {
        float4 w0 = *(const float4*)&Wsrc[wo * C_DIM + kc + wk];
        float4 w1 = *(const float4*)&Wsrc[wo * C_DIM + kc + wk + 4];
        float4 x0 = *(const float4*)&xb[(size_t)(kc + xk) * N_DIM + n0 + xn];
        float4 x1 = *(const float4*)&xb[(size_t)(kc + xk) * N_DIM + n0 + xn + 4];
        __syncthreads();   // previous tile's readers done before overwrite
        // transpose W into LDS (scalar stores, 2-way bank alias = free)
        Wt[wk + 0][wo] = w0.x;  Wt[wk + 1][wo] = w0.y;
        Wt[wk + 2][wo] = w0.z;  Wt[wk + 3][wo] = w0.w;
        Wt[wk + 4][wo] = w1.x;  Wt[wk + 5][wo] = w1.y;
        Wt[wk + 6][wo] = w1.z;  Wt[wk + 7][wo] = w1.w;
        *(float4*)&Xt[xk][xn]     = x0;
        *(float4*)&Xt[xk][xn + 4] = x1;
        __syncthreads();

        #pragma unroll 2
        for (int k = 0; k < 16; k++) {
            float4 a0 = *(const float4*)&Wt[k][ty * 8];
            float4 a1 = *(const float4*)&Wt[k][ty * 8 + 4];
            float4 b0 = *(const float4*)&Xt[k][tx * 8];
            float4 b1 = *(const float4*)&Xt[k][tx * 8 + 4];
            float a[8] = {a0.x, a0.y, a0.z, a0.w, a1.x, a1.y, a1.z, a1.w};
            float bv[8] = {b0.x, b0.y, b0.z, b0.w, b1.x, b1.y, b1.z, b1.w};
            #pragma unroll
            for (int i = 0; i < 8; i++)
                #pragma unroll
                for (int j = 0; j < 8; j++)
                    acc[i][j] = fmaf(a[i], bv[j], acc[i][j]);
        }
    }

    // permuted store: ws[vm][o2][t], n -> (t = n/50, vm = n%50)
    #pragma unroll
    for (int j = 0; j < 8; j++) {
        const int n = n0 + tx * 8 + j;
        const int t = n / VM;
        const int vm = n - t * VM;
        float* col = outb + (size_t)vm * (O_DIM * 2 * T_DIM)
                   + (size_t)(o0 + ty * 8) * T_DIM + t;
        #pragma unroll
        for (int i = 0; i < 8; i++)
            col[(size_t)i * T_DIM] = acc[i][j];
    }
}

// ------------- Stage 2: scores = s1^T s2 (64x256 tile) + fused softmax -------
__global__ __launch_bounds__(512)
void stage2_softmax(const float* __restrict__ ws, float* __restrict__ out, int b0) {
    const int bl = blockIdx.z;
    const int b  = b0 + bl;
    const int vm = blockIdx.y;            // = v*2 + m
    const int t0 = blockIdx.x * 64;
    const float* s12b = ws + (size_t)bl * VM * (O_DIM * 2 * T_DIM)
                      + (size_t)vm * (O_DIM * 2 * T_DIM);
    const float* s1 = s12b;                       // [128][256] : o x t
    const float* s2 = s12b + (size_t)O_DIM * T_DIM; // [128][256] : o x s

    __shared__ float At[32][68];    // [k][t]  (64 + 4 pad)
    __shared__ float Bt[32][260];   // [k][s]  (256 + 4 pad)

    const int tid = threadIdx.x;
    const int ty = tid >> 5;        // 0..15 : t micro-rows
    const int tx = tid & 31;        // 0..31 : s micro-cols (one 32-lane group)

    const int lr = tid >> 4;        // 0..31  load row (o within chunk)
    const int lt = (tid & 15) * 4;  // A col
    const int ls = (tid & 15) * 16; // B col base

    float acc[4][8] = {};

    for (int kc = 0; kc < O_DIM; kc += 32) {
        float4 av  = *(const float4*)&s1[(size_t)(kc + lr) * T_DIM + t0 + lt];
        float4 bv0 = *(const float4*)&s2[(size_t)(kc + lr) * T_DIM + ls];
        float4 bv1 = *(const float4*)&s2[(size_t)(kc + lr) * T_DIM + ls + 4];
        float4 bv2 = *(const float4*)&s2[(size_t)(kc + lr) * T_DIM + ls + 8];
        float4 bv3 = *(const float4*)&s2[(size_t)(kc + lr) * T_DIM + ls + 12];
        __syncthreads();
        *(float4*)&At[lr][lt]      = av;
        *(float4*)&Bt[lr][ls]      = bv0;
        *(float4*)&Bt[lr][ls + 4]  = bv1;
        *(float4*)&Bt[lr][ls + 8]  = bv2;
        *(float4*)&Bt[lr][ls + 12] = bv3;
        __syncthreads();

        #pragma unroll 2
        for (int k = 0; k < 32; k++) {
            float4 a  = *(const float4*)&At[k][ty * 4];
            float4 b0 = *(const float4*)&Bt[k][tx * 8];
            float4 b1 = *(const float4*)&Bt[k][tx * 8 + 4];
            float av_[4] = {a.x, a.y, a.z, a.w};
            float bv_[8] = {b0.x, b0.y, b0.z, b0.w, b1.x, b1.y, b1.z, b1.w};
            #pragma unroll
            for (int i = 0; i < 4; i++)
                #pragma unroll
                for (int j = 0; j < 8; j++)
                    acc[i][j] = fmaf(av_[i], bv_[j], acc[i][j]);
        }
    }

    // fused softmax over s (row = fixed t); row spread over 32 lanes x 8 vals
    const int mm = vm & 1;
    const int vv = vm >> 1;
    const size_t rowbase0 = (((size_t)b * M_DIM + mm) * V_DIM + vv) * T_DIM;

    #pragma unroll
    for (int i = 0; i < 4; i++) {
        float mx = -INFINITY;
        #pragma unroll
        for (int j = 0; j < 8; j++) mx = fmaxf(mx, acc[i][j]);
        #pragma unroll
        for (int d = 16; d >= 1; d >>= 1) mx = fmaxf(mx, __shfl_xor(mx, d));
        float p[8];
        float l = 0.f;
        #pragma unroll
        for (int j = 0; j < 8; j++) { p[j] = __expf(acc[i][j] - mx); l += p[j]; }
        #pragma unroll
        for (int d = 16; d >= 1; d >>= 1) l += __shfl_xor(l, d);
        const float inv = 1.0f / l;
        float4 r0 = {p[0] * inv, p[1] * inv, p[2] * inv, p[3] * inv};
        float4 r1 = {p[4] * inv, p[5] * inv, p[6] * inv, p[7] * inv};
        float* orow = out + (rowbase0 + t0 + ty * 4 + i) * T_DIM + tx * 8;
        *(float4*)orow       = r0;
        *((float4*)orow + 1) = r1;
    }
}

extern "C" void kernel_launch(void* const* d_in, const int* in_sizes, int n_in,
                              void* d_out, int out_size, void* d_ws, size_t ws_size,
                              hipStream_t stream) {
    const float* x  = (const float*)d_in[0];
    const float* W1 = (const float*)d_in[1];
    const float* W2 = (const float*)d_in[2];
    float* out = (float*)d_out;
    float* ws  = (float*)d_ws;

    const size_t per_b_bytes = (size_t)VM * O_DIM * 2 * T_DIM * sizeof(float); // 13.1 MB
    int nb = (int)(ws_size / per_b_bytes);
    if (nb < 1) return;        // ws too small to run at all
    if (nb > 16) nb = 16;

    for (int b0 = 0; b0 < 16; b0 += nb) {
        const int n = (16 - b0 < nb) ? (16 - b0) : nb;
        stage1_gemm<<<dim3(N_DIM / 128, 2, n), 256, 0, stream>>>(x, W1, W2, ws, b0);
        stage2_softmax<<<dim3(T_DIM / 64, VM, n), 512, 0, stream>>>(ws, out, b0);
    }
}

// Round 2
// 871.466 us; speedup vs baseline: 1.3502x; 1.3502x over previous
//
#include <hip/hip_runtime.h>
#include <math.h>

// out[b,m,v,t,s] = softmax_s( sum_o (W1·X)[o,t] * (W2·X)[o,s] ),
// X[c,t] = x[b,c,t,v,m].  B=16, C=256, T=256, V=25, M=2, O=128.
//
// Stage 1 (R2 rewrite): block = (vm, 64-t-tile, b). Computes s12[o2=256][64 t]
//   for its fixed vm. X global reads are 200B-strided scalars (L2 absorbs the
//   line sharing across neighboring vm blocks); output stores are COALESCED
//   float4 into ws[b][vm][o2][t] — kills the R1 8.3x write amplification.
// Stage 2: per (b,vm): scores = s1^T s2 (256x256, K=128) + fused row softmax.
// Multi-pass over b sized by ws_size (13.1 MB per b needed).

#define C_DIM 256
#define T_DIM 256
#define V_DIM 25
#define M_DIM 2
#define O_DIM 128
#define O2    (O_DIM * 2)             /* 256 */
#define N_DIM (T_DIM * V_DIM * M_DIM) /* 12800 */
#define VM    (V_DIM * M_DIM)         /* 50 */
#define KC    32

// ---------------- Stage 1: per-vm 256(o2) x 64(t) tile, coalesced store -----
__global__ __launch_bounds__(256)
void stage1_gemm(const float* __restrict__ x, const float* __restrict__ W1,
                 const float* __restrict__ W2, float* __restrict__ ws, int b0) {
    const int b  = b0 + blockIdx.z;
    const int vm = blockIdx.y;
    const int t0 = blockIdx.x * 64;
    const float* xb = x + (size_t)b * C_DIM * N_DIM;
    float* outv = ws + ((size_t)blockIdx.z * VM + vm) * ((size_t)O2 * T_DIM);

    __shared__ float Wt[KC][260];  // [k][o2]  row stride 260 (4-float aligned, +4 pad)
    __shared__ float Xt[KC][68];   // [k][t]   row stride 68

    const int tid = threadIdx.x;

    // W load: each thread owns one o2 row, loads 8 float4 along k (2 full lines)
    const int wo = tid;                    // 0..255
    const float* wrow = (wo < O_DIM) ? (W1 + (size_t)wo * C_DIM)
                                     : (W2 + (size_t)(wo - O_DIM) * C_DIM);
    // X load: t = tid&63, k sub-rows (tid>>6)*8 .. +7 ; 200B-strided scalars
    const int xt  = tid & 63;
    const int xkb = (tid >> 6) * 8;

    // compute micro-tile: 8 o2 x 8 t per thread
    const int to = tid >> 3;   // 0..31 : o2 base = to*8
    const int tt = tid & 7;    // t cols: tt*4+j (j<4) and 32+tt*4+(j-4)

    float acc[8][8] = {};

    for (int kc = 0; kc < C_DIM; kc += KC) {
        float4 wv[8];
        #pragma unroll
        for (int j = 0; j < 8; j++)
            wv[j] = *(const float4*)&wrow[kc + 4 * j];
        float xv[8];
        #pragma unroll
        for (int j = 0; j < 8; j++)
            xv[j] = xb[(size_t)(kc + xkb + j) * N_DIM + (size_t)(t0 + xt) * VM + vm];

        __syncthreads();   // previous tile's readers done before overwrite
        #pragma unroll
        for (int j = 0; j < 8; j++) {      // transpose W into [k][o]; 2-way banks = free
            Wt[4 * j + 0][wo] = wv[j].x;
            Wt[4 * j + 1][wo] = wv[j].y;
            Wt[4 * j + 2][wo] = wv[j].z;
            Wt[4 * j + 3][wo] = wv[j].w;
        }
        #pragma unroll
        for (int j = 0; j < 8; j++)        // banks = (4k + t)%32, 2/bank = free
            Xt[xkb + j][xt] = xv[j];
        __syncthreads();

        #pragma unroll 4
        for (int k = 0; k < KC; k++) {
            float4 a0 = *(const float4*)&Wt[k][to * 8];      // 8-lane broadcast
            float4 a1 = *(const float4*)&Wt[k][to * 8 + 4];
            float4 b0 = *(const float4*)&Xt[k][tt * 4];      // banks 4*tt, no conflict
            float4 b1 = *(const float4*)&Xt[k][tt * 4 + 32];
            float a[8]  = {a0.x, a0.y, a0.z, a0.w, a1.x, a1.y, a1.z, a1.w};
            float bv[8] = {b0.x, b0.y, b0.z, b0.w, b1.x, b1.y, b1.z, b1.w};
            #pragma unroll
            for (int i = 0; i < 8; i++)
                #pragma unroll
                for (int j = 0; j < 8; j++)
                    acc[i][j] = fmaf(a[i], bv[j], acc[i][j]);
        }
    }

    // coalesced store: ws[vm][o2][t0 + ...], two float4 per o-row per thread
    #pragma unroll
    for (int i = 0; i < 8; i++) {
        float* row = outv + (size_t)(to * 8 + i) * T_DIM + t0;
        float4 r0 = {acc[i][0], acc[i][1], acc[i][2], acc[i][3]};
        float4 r1 = {acc[i][4], acc[i][5], acc[i][6], acc[i][7]};
        *(float4*)&row[tt * 4]      = r0;
        *(float4*)&row[tt * 4 + 32] = r1;
    }
}

// ------------- Stage 2: scores = s1^T s2 (64x256 tile) + fused softmax -------
__global__ __launch_bounds__(512)
void stage2_softmax(const float* __restrict__ ws, float* __restrict__ out, int b0) {
    const int bl = blockIdx.z;
    const int b  = b0 + bl;
    const int vm = blockIdx.y;            // = v*2 + m
    const int t0 = blockIdx.x * 64;
    const float* s12b = ws + ((size_t)bl * VM + vm) * ((size_t)O2 * T_DIM);
    const float* s1 = s12b;                          // [128][256] : o x t
    const float* s2 = s12b + (size_t)O_DIM * T_DIM;  // [128][256] : o x s

    __shared__ float At[32][68];    // [k][t]  (64 + 4 pad)
    __shared__ float Bt[32][260];   // [k][s]  (256 + 4 pad)

    const int tid = threadIdx.x;
    const int ty = tid >> 5;        // 0..15 : t micro-rows
    const int tx = tid & 31;        // 0..31 : s micro-cols

    const int lr = tid >> 4;        // 0..31  load row (o within chunk)
    const int lt = (tid & 15) * 4;  // A col
    const int ls = (tid & 15) * 16; // B col base

    float acc[4][8] = {};

    for (int kc = 0; kc < O_DIM; kc += 32) {
        float4 av  = *(const float4*)&s1[(size_t)(kc + lr) * T_DIM + t0 + lt];
        float4 bv0 = *(const float4*)&s2[(size_t)(kc + lr) * T_DIM + ls];
        float4 bv1 = *(const float4*)&s2[(size_t)(kc + lr) * T_DIM + ls + 4];
        float4 bv2 = *(const float4*)&s2[(size_t)(kc + lr) * T_DIM + ls + 8];
        float4 bv3 = *(const float4*)&s2[(size_t)(kc + lr) * T_DIM + ls + 12];
        __syncthreads();
        *(float4*)&At[lr][lt]      = av;
        *(float4*)&Bt[lr][ls]      = bv0;
        *(float4*)&Bt[lr][ls + 4]  = bv1;
        *(float4*)&Bt[lr][ls + 8]  = bv2;
        *(float4*)&Bt[lr][ls + 12] = bv3;
        __syncthreads();

        #pragma unroll 2
        for (int k = 0; k < 32; k++) {
            float4 a  = *(const float4*)&At[k][ty * 4];
            float4 b0 = *(const float4*)&Bt[k][tx * 8];
            float4 b1 = *(const float4*)&Bt[k][tx * 8 + 4];
            float av_[4] = {a.x, a.y, a.z, a.w};
            float bv_[8] = {b0.x, b0.y, b0.z, b0.w, b1.x, b1.y, b1.z, b1.w};
            #pragma unroll
            for (int i = 0; i < 4; i++)
                #pragma unroll
                for (int j = 0; j < 8; j++)
                    acc[i][j] = fmaf(av_[i], bv_[j], acc[i][j]);
        }
    }

    // fused softmax over s (row = fixed t); row spread over 32 lanes x 8 vals
    const int mm = vm & 1;
    const int vv = vm >> 1;
    const size_t rowbase0 = (((size_t)b * M_DIM + mm) * V_DIM + vv) * T_DIM;

    #pragma unroll
    for (int i = 0; i < 4; i++) {
        float mx = -INFINITY;
        #pragma unroll
        for (int j = 0; j < 8; j++) mx = fmaxf(mx, acc[i][j]);
        #pragma unroll
        for (int d = 16; d >= 1; d >>= 1) mx = fmaxf(mx, __shfl_xor(mx, d));
        float p[8];
        float l = 0.f;
        #pragma unroll
        for (int j = 0; j < 8; j++) { p[j] = __expf(acc[i][j] - mx); l += p[j]; }
        #pragma unroll
        for (int d = 16; d >= 1; d >>= 1) l += __shfl_xor(l, d);
        const float inv = 1.0f / l;
        float4 r0 = {p[0] * inv, p[1] * inv, p[2] * inv, p[3] * inv};
        float4 r1 = {p[4] * inv, p[5] * inv, p[6] * inv, p[7] * inv};
        float* orow = out + (rowbase0 + t0 + ty * 4 + i) * T_DIM + tx * 8;
        *(float4*)orow       = r0;
        *((float4*)orow + 1) = r1;
    }
}

extern "C" void kernel_launch(void* const* d_in, const int* in_sizes, int n_in,
                              void* d_out, int out_size, void* d_ws, size_t ws_size,
                              hipStream_t stream) {
    const float* x  = (const float*)d_in[0];
    const float* W1 = (const float*)d_in[1];
    const float* W2 = (const float*)d_in[2];
    float* out = (float*)d_out;
    float* ws  = (float*)d_ws;

    const size_t per_b_bytes = (size_t)VM * O2 * T_DIM * sizeof(float); // 13.1 MB
    int nb = (int)(ws_size / per_b_bytes);
    if (nb < 1) return;
    if (nb > 16) nb = 16;

    for (int b0 = 0; b0 < 16; b0 += nb) {
        const int n = (16 - b0 < nb) ? (16 - b0) : nb;
        stage1_gemm<<<dim3(T_DIM / 64, VM, n), 256, 0, stream>>>(x, W1, W2, ws, b0);
        stage2_softmax<<<dim3(T_DIM / 64, VM, n), 512, 0, stream>>>(ws, out, b0);
    }
}